// Round 11
// baseline (149.894 us; speedup 1.0000x reference)
//
#include <hip/hip_runtime.h>
#include <hip/hip_bf16.h>

#define NB 16
#define DMODEL 1024
#define HALFD 512
#define PNUM 4096
#define PLEN 32
#define SEQ 2048
#define SIM 64
#define NPATCH 64
#define NROWS (NB*SEQ)        // 32768 sequence rows
#define MROWS (NB*NPATCH)     // 1024 (b,p) rows
#define KDIM (PLEN*HALFD)     // 16384
#define OUT0 ((size_t)NB*SEQ*DMODEL)

typedef __attribute__((ext_vector_type(8))) short s8v;          // 8 bf16 (4 VGPR)
typedef __attribute__((ext_vector_type(4))) float f32x4;
typedef __attribute__((ext_vector_type(8))) unsigned short ush8;
typedef unsigned long long u64;

__device__ __forceinline__ unsigned short f2bf(float f) {
    __hip_bfloat16 h = __float2bfloat16(f);
    return *reinterpret_cast<unsigned short*>(&h);
}
__device__ __forceinline__ float bf2f(unsigned short u) {
    __hip_bfloat16 h = *reinterpret_cast<__hip_bfloat16*>(&u);
    return __bfloat162float(h);
}
__device__ __forceinline__ u64 umax64(u64 a, u64 b) { return a > b ? a : b; }
__device__ __forceinline__ u64 umin64(u64 a, u64 b) { return a < b ? a : b; }
__device__ __forceinline__ u64 clean6(u64 v, int lane) {
    #pragma unroll
    for (int j = 32; j; j >>= 1) {
        u64 o = __shfl_xor(v, j);
        v = ((lane & j) == 0) ? umax64(v, o) : umin64(v, o);
    }
    return v;
}

// ---------------- K0: fwT fragment-pack (0..255) | low (256..767) | copy (768..1791) ----------------
// fwT packed in MFMA B-fragment order: frag[kblk][fn][lane][j] — lane-contiguous 16B.
union PrepShared {
    float tile[64][68];        // 17.4 KB (pack role)
    double gpm[513];           // 4.1 KB (low role)
};
__global__ __launch_bounds__(256) void k_prep(
        const float* __restrict__ gp_w, const float* __restrict__ gp_b,
        const float* __restrict__ fw, const float* __restrict__ src,
        unsigned short* __restrict__ fwT_hi, unsigned short* __restrict__ fwT_lo,
        double* __restrict__ low, float* __restrict__ out) {
    __shared__ PrepShared u;
    int bid = blockIdx.x, t = threadIdx.x;
    if (bid < 256) {
        // ---- pack fw -> fragment order, bf16 hi/lo ----
        int k0 = bid * 64;
        int i = t >> 2;
        #pragma unroll
        for (int q = 0; q < 4; ++q) {
            int c = (t & 3) + q*4;
            float4 v = *reinterpret_cast<const float4*>(fw + (size_t)(k0 + i)*SIM + c*4);
            *reinterpret_cast<float4*>(&u.tile[i][c*4]) = v;
        }
        __syncthreads();
        #pragma unroll
        for (int c2 = 0; c2 < 2; ++c2) {
            int e = c2*256 + t;
            int kl = e >> 8, fn = (e >> 6) & 3, l = e & 63;
            int kk0 = kl*32 + ((l >> 4) * 8), n = fn*16 + (l & 15);
            ush8 hv, lv;
            #pragma unroll
            for (int j = 0; j < 8; ++j) {
                float f = u.tile[kk0 + j][n];
                unsigned short hb = f2bf(f);
                hv[j] = hb;
                lv[j] = f2bf(f - bf2f(hb));
            }
            size_t dst = ((size_t)((2*bid + kl)*4 + fn)*64 + l)*8;
            *reinterpret_cast<ush8*>(fwT_hi + dst) = hv;
            *reinterpret_cast<ush8*>(fwT_lo + dst) = lv;
        }
    } else if (bid < 768) {
        // ---- low role: self-contained gp means + 4 batch-0 row dots ----
        for (int h = t; h < HALFD; h += 256) {
            double s = 0.0;
            #pragma unroll
            for (int j = 0; j < 10; ++j) s += (double)gp_w[h*10 + j];
            u.gpm[h] = s / 10.0;
        }
        if (t == 0) {
            double sb = 0.0;
            #pragma unroll
            for (int j = 0; j < 10; ++j) sb += (double)gp_b[j];
            u.gpm[512] = sb / 10.0;
        }
        __syncthreads();
        int r = (bid - 256)*4 + (t >> 6);      // 0..2047
        int lane = t & 63;
        const float4* s4 = reinterpret_cast<const float4*>(src + (size_t)r * DMODEL);
        float4 x0 = s4[128 + lane];
        float4 x1 = s4[192 + lane];
        const double* g0 = u.gpm + lane*4;
        const double* g1 = u.gpm + 256 + lane*4;
        double d = (double)x0.x*g0[0] + (double)x0.y*g0[1] + (double)x0.z*g0[2] + (double)x0.w*g0[3]
                 + (double)x1.x*g1[0] + (double)x1.y*g1[1] + (double)x1.z*g1[2] + (double)x1.w*g1[3];
        #pragma unroll
        for (int o = 32; o; o >>= 1) d += __shfl_xor(d, o);
        if (lane == 0) low[r] = d + u.gpm[512];
    } else {
        // ---- copy role: out[:, :512] = src[:, :512] ----
        int cb = bid - 768;
        size_t total = (size_t)NROWS * 128;
        const float4* s4 = reinterpret_cast<const float4*>(src);
        float4* o4 = reinterpret_cast<float4*>(out);
        for (size_t idx = (size_t)cb*256 + t; idx < total; idx += (size_t)1024*256) {
            size_t r = idx >> 7, c = idx & 127;
            o4[r*256 + c] = s4[r*256 + c];
        }
    }
}

// ---------------- K2: topk — wave-register bitonic ----------------
__global__ __launch_bounds__(256) void k_topk(
        const double* __restrict__ low, const float* __restrict__ pool,
        u64* __restrict__ cand) {
    __shared__ double lowp[PLEN];
    __shared__ u64 wl[4][64];
    int t = threadIdx.x, lane = t & 63, w = t >> 6;
    int p = blockIdx.x >> 3, q = blockIdx.x & 7;
    if (t < PLEN) lowp[t] = low[p*PLEN + t];
    __syncthreads();
    u64 v[2];
    #pragma unroll
    for (int cc = 0; cc < 2; ++cc) {
        int n = q*512 + (w*2 + cc)*64 + lane;
        const float4* p4 = reinterpret_cast<const float4*>(pool + (size_t)n*PLEN);
        double s = 0.0;
        #pragma unroll
        for (int r2 = 0; r2 < 8; ++r2) {
            float4 vv = p4[r2];
            s += (double)vv.x*lowp[r2*4] + (double)vv.y*lowp[r2*4+1]
               + (double)vv.z*lowp[r2*4+2] + (double)vv.w*lowp[r2*4+3];
        }
        u64 ub = (u64)__double_as_longlong(s);
        u64 okey = ub ^ (((u64)((long long)ub >> 63)) | 0x8000000000000000ULL);
        v[cc] = (okey & ~0xFFFULL) | (u64)(0xFFF - n);
    }
    #pragma unroll
    for (int kk = 2; kk <= 64; kk <<= 1) {
        #pragma unroll
        for (int j = kk >> 1; j; j >>= 1) {
            #pragma unroll
            for (int cc = 0; cc < 2; ++cc) {
                u64 o = __shfl_xor(v[cc], j);
                bool keepMax = ((lane & kk) == 0) == ((lane & j) == 0);
                v[cc] = keepMax ? umax64(v[cc], o) : umin64(v[cc], o);
            }
        }
    }
    u64 rb = __shfl(v[1], 63 - lane);
    u64 m = umax64(v[0], rb);
    m = clean6(m, lane);
    wl[w][lane] = m;
    __syncthreads();
    if (w == 0) {
        u64 a = umax64(wl[0][lane], wl[1][63 - lane]); a = clean6(a, lane);
        u64 b = umax64(wl[2][lane], wl[3][63 - lane]); b = clean6(b, lane);
        u64 r2 = __shfl(b, 63 - lane);
        u64 f = umax64(a, r2); f = clean6(f, lane);
        cand[(size_t)(p*8 + q)*SIM + lane] = f;
    }
}

// ---------------- K3: logits MFMA — LDS-staged A (coalesced), fragment-packed B ----------------
__global__ __launch_bounds__(256) void k_logits(
        const float* __restrict__ src,
        const unsigned short* __restrict__ fwT_hi, const unsigned short* __restrict__ fwT_lo,
        float* __restrict__ part, int nks) {
    __shared__ float xs[64][68];
    int t = threadIdx.x, lane = t & 63, w = t >> 6;
    int mt = blockIdx.x / nks, ks = blockIdx.x - mt*nks;
    int kchunk = KDIM / nks, nstep = kchunk >> 6;
    int r0 = mt*64;
    int kblk_base = (ks*kchunk) >> 5;
    f32x4 acc[4] = {};
    float4 pre[4];
    {   // prefetch step 0
        int k0s = ks*kchunk, lp = k0s >> 9, h0 = k0s & 511;
        #pragma unroll
        for (int q = 0; q < 4; ++q) {
            int idx = q*256 + t, rr = idx >> 4, f4 = idx & 15;
            int R = r0 + rr, bb = R >> 6, pp = R & 63;
            pre[q] = *reinterpret_cast<const float4*>(
                src + ((size_t)(bb*SEQ + pp*PLEN + lp))*DMODEL + HALFD + h0 + f4*4);
        }
    }
    for (int step = 0; step < nstep; ++step) {
        #pragma unroll
        for (int q = 0; q < 4; ++q) {
            int idx = q*256 + t, rr = idx >> 4, f4 = idx & 15;
            *reinterpret_cast<float4*>(&xs[rr][f4*4]) = pre[q];
        }
        __syncthreads();
        if (step + 1 < nstep) {
            int k0s = ks*kchunk + (step+1)*64, lp = k0s >> 9, h0 = k0s & 511;
            #pragma unroll
            for (int q = 0; q < 4; ++q) {
                int idx = q*256 + t, rr = idx >> 4, f4 = idx & 15;
                int R = r0 + rr, bb = R >> 6, pp = R & 63;
                pre[q] = *reinterpret_cast<const float4*>(
                    src + ((size_t)(bb*SEQ + pp*PLEN + lp))*DMODEL + HALFD + h0 + f4*4);
            }
        }
        int arow = w*16 + (lane & 15);
        int kg8 = (lane >> 4) * 8;
        #pragma unroll
        for (int kbl = 0; kbl < 2; ++kbl) {
            float4 a0 = *reinterpret_cast<float4*>(&xs[arow][kbl*32 + kg8]);
            float4 a1 = *reinterpret_cast<float4*>(&xs[arow][kbl*32 + kg8 + 4]);
            s8v ah, al;
            float fa[8] = {a0.x,a0.y,a0.z,a0.w,a1.x,a1.y,a1.z,a1.w};
            #pragma unroll
            for (int j = 0; j < 8; ++j) {
                unsigned short hb = f2bf(fa[j]);
                ah[j] = (short)hb;
                al[j] = (short)f2bf(fa[j] - bf2f(hb));
            }
            int kblk = kblk_base + step*2 + kbl;
            #pragma unroll
            for (int fn = 0; fn < 4; ++fn) {
                size_t off = ((size_t)(kblk*4 + fn)*64 + lane)*8;
                s8v bh = *reinterpret_cast<const s8v*>(fwT_hi + off);
                s8v bl = *reinterpret_cast<const s8v*>(fwT_lo + off);
                acc[fn] = __builtin_amdgcn_mfma_f32_16x16x32_bf16(ah, bh, acc[fn], 0, 0, 0);
                acc[fn] = __builtin_amdgcn_mfma_f32_16x16x32_bf16(ah, bl, acc[fn], 0, 0, 0);
                acc[fn] = __builtin_amdgcn_mfma_f32_16x16x32_bf16(al, bh, acc[fn], 0, 0, 0);
            }
        }
        __syncthreads();
    }
    float* pp = part + (size_t)(mt*nks + ks)*4096;
    int ml = lane & 15, kg = lane >> 4;
    #pragma unroll
    for (int fn = 0; fn < 4; ++fn)
        #pragma unroll
        for (int r = 0; r < 4; ++r)
            pp[(w*16 + kg*4 + r)*64 + fn*16 + ml] = acc[fn][r];
}

// ---------------- K5: softmax (0..1023) + topk final merge (1024..1087) ----------------
__global__ __launch_bounds__(64) void k_softmax(
        const float* __restrict__ part, const float* __restrict__ fb,
        float* __restrict__ route, const u64* __restrict__ cand,
        int* __restrict__ sel, int nks) {
    if (blockIdx.x < MROWS) {
        int row = blockIdx.x;
        int s = threadIdx.x;
        int mt = row >> 6, i = row & 63;
        float v = fb[s];
        for (int ks = 0; ks < nks; ++ks)
            v += part[(size_t)(mt*nks + ks)*4096 + i*64 + s];
        float m = v;
        #pragma unroll
        for (int o = 32; o; o >>= 1) m = fmaxf(m, __shfl_xor(m, o));
        float e = expf(v - m);
        float sum = e;
        #pragma unroll
        for (int o = 32; o; o >>= 1) sum += __shfl_xor(sum, o);
        route[row*64 + s] = e / sum;
    } else {
        int p = blockIdx.x - MROWS;
        int lane = threadIdx.x;
        const u64* c = cand + (size_t)p*8*SIM;
        u64 a = umax64(c[lane],         c[1*SIM + 63 - lane]); a = clean6(a, lane);
        u64 b = umax64(c[2*SIM + lane], c[3*SIM + 63 - lane]); b = clean6(b, lane);
        u64 d = umax64(c[4*SIM + lane], c[5*SIM + 63 - lane]); d = clean6(d, lane);
        u64 e = umax64(c[6*SIM + lane], c[7*SIM + 63 - lane]); e = clean6(e, lane);
        u64 ab = umax64(a, __shfl(b, 63 - lane)); ab = clean6(ab, lane);
        u64 de = umax64(d, __shfl(e, 63 - lane)); de = clean6(de, lane);
        u64 f  = umax64(ab, __shfl(de, 63 - lane)); f = clean6(f, lane);
        sel[p*SIM + lane] = 0xFFF - (int)(f & 0xFFFULL);
    }
}

// ---------------- K6: fuse + recover GEMM + padding + zeros ----------------
__global__ __launch_bounds__(256) void k_out(
        const float* __restrict__ route, const int* __restrict__ sel,
        const float* __restrict__ pool, const float* __restrict__ rw,
        const float* __restrict__ rb, float* __restrict__ out, float* __restrict__ pad) {
    __shared__ float A_T[SIM][36];
    __shared__ float rws[64][132];
    __shared__ float routeS[64];
    int row = blockIdx.x;
    int b = row >> 6, p = row & 63;
    int t = threadIdx.x;
    if (t < 64) routeS[t] = route[row*64 + t];
    __syncthreads();
    #pragma unroll
    for (int q = 0; q < 8; ++q) {
        int e = t + q*256;
        int s = e >> 5, l = e & 31;
        A_T[s][l] = routeS[s] * pool[(size_t)sel[p*SIM + s]*PLEN + l];
    }
    __syncthreads();
    if (t < 32) {
        float ps = 0.f;
        #pragma unroll
        for (int s = 0; s < 64; ++s) ps += A_T[s][t];
        pad[(size_t)b*2*SEQ + SEQ + p*PLEN + t] = ps;
    } else if (t < 64) {
        pad[(size_t)b*2*SEQ + p*PLEN + (t - 32)] = 0.f;
    }
    int l0  = (t >> 5) * 4;
    int h04 = (t & 31) * 4;
    for (int hc = 0; hc < HALFD; hc += 128) {
        #pragma unroll
        for (int q = 0; q < 8; ++q) {
            int fi = t + q*256;
            int r = fi >> 5, c4 = fi & 31;
            float4 v = *reinterpret_cast<const float4*>(rw + (size_t)r*HALFD + hc + c4*4);
            *reinterpret_cast<float4*>(&rws[r][c4*4]) = v;
        }
        __syncthreads();
        float acc[4][4] = {};
        #pragma unroll 8
        for (int s = 0; s < 64; ++s) {
            float4 av = *reinterpret_cast<float4*>(&A_T[s][l0]);
            float4 wv = *reinterpret_cast<float4*>(&rws[s][h04]);
            acc[0][0] += av.x*wv.x; acc[0][1] += av.x*wv.y; acc[0][2] += av.x*wv.z; acc[0][3] += av.x*wv.w;
            acc[1][0] += av.y*wv.x; acc[1][1] += av.y*wv.y; acc[1][2] += av.y*wv.z; acc[1][3] += av.y*wv.w;
            acc[2][0] += av.z*wv.x; acc[2][1] += av.z*wv.y; acc[2][2] += av.z*wv.z; acc[2][3] += av.z*wv.w;
            acc[3][0] += av.w*wv.x; acc[3][1] += av.w*wv.y; acc[3][2] += av.w*wv.z; acc[3][3] += av.w*wv.w;
        }
        int h = hc + h04;
        float4 bias = *reinterpret_cast<const float4*>(rb + h);
        #pragma unroll
        for (int i = 0; i < 4; ++i) {
            int l = l0 + i;
            float4 v = { acc[i][0] + bias.x, acc[i][1] + bias.y,
                         acc[i][2] + bias.z, acc[i][3] + bias.w };
            *reinterpret_cast<float4*>(out + ((size_t)(b*SEQ + p*PLEN + l))*DMODEL + HALFD + h) = v;
        }
        __syncthreads();
    }
}

static const void* by_size(void* const* d_in, const int* in_sizes, int n_in,
                           int want, int fallback) {
    for (int i = 0; i < n_in; ++i) if (in_sizes[i] == want) return d_in[i];
    return d_in[fallback];
}

extern "C" void kernel_launch(void* const* d_in, const int* in_sizes, int n_in,
                              void* d_out, int out_size, void* d_ws, size_t ws_size,
                              hipStream_t stream) {
    const float* src  = (const float*)by_size(d_in, in_sizes, n_in, NB*SEQ*DMODEL, 0);
    const float* pool = (const float*)by_size(d_in, in_sizes, n_in, PNUM*PLEN, 1);
    const float* fw   = (const float*)by_size(d_in, in_sizes, n_in, KDIM*SIM, 2);
    const float* fb   = (const float*)by_size(d_in, in_sizes, n_in, SIM, 3);
    const float* rw   = (const float*)by_size(d_in, in_sizes, n_in, SIM*HALFD, 4);
    const float* rb   = (const float*)by_size(d_in, in_sizes, n_in, HALFD, 5);
    const float* gpw  = (const float*)by_size(d_in, in_sizes, n_in, HALFD*10, 6);
    const float* gpb  = (const float*)by_size(d_in, in_sizes, n_in, 10, 7);
    float* out = (float*)d_out;
    float* pad = out + OUT0;

    int nks = (ws_size >= (size_t)(24u << 20)) ? 64 : 8;

    unsigned short* fwT_hi = (unsigned short*)d_ws;                     // 2 MB
    unsigned short* fwT_lo = fwT_hi + (size_t)SIM*KDIM;                 // 2 MB
    double* low  = (double*)(fwT_lo + (size_t)SIM*KDIM);                // 16 KB
    u64*   cand  = (u64*)(low + 2048);                                  // 256 KB
    int*   sel   = (int*)(cand + (size_t)NPATCH*8*SIM);                 // 16 KB
    float* route = (float*)(sel + 4096);                                // 256 KB
    float* part  = route + MROWS*SIM;                                   // nks * 256 KB

    hipLaunchKernelGGL(k_prep,    dim3(1792),          dim3(256), 0, stream,
                       gpw, gpb, fw, src, fwT_hi, fwT_lo, low, out);
    hipLaunchKernelGGL(k_topk,    dim3(512),           dim3(256), 0, stream, low, pool, cand);
    hipLaunchKernelGGL(k_logits,  dim3(16*nks),        dim3(256), 0, stream, src, fwT_hi, fwT_lo, part, nks);
    hipLaunchKernelGGL(k_softmax, dim3(MROWS+NPATCH),  dim3(64),  0, stream, part, fb, route, cand, sel, nks);
    hipLaunchKernelGGL(k_out,     dim3(MROWS),         dim3(256), 0, stream, route, sel, pool, rw, rb, out, pad);
}

// Round 13
// 112.928 us; speedup vs baseline: 1.3273x; 1.3273x over previous
//
#include <hip/hip_runtime.h>
#include <hip/hip_bf16.h>

#define NB 16
#define DMODEL 1024
#define HALFD 512
#define PNUM 4096
#define PLEN 32
#define SEQ 2048
#define SIM 64
#define NPATCH 64
#define NROWS (NB*SEQ)        // 32768 sequence rows
#define MROWS (NB*NPATCH)     // 1024 (b,p) rows
#define KDIM (PLEN*HALFD)     // 16384
#define OUT0 ((size_t)NB*SEQ*DMODEL)

typedef __attribute__((ext_vector_type(8))) short s8v;          // 8 bf16 (4 VGPR)
typedef __attribute__((ext_vector_type(4))) float f32x4;
typedef __attribute__((ext_vector_type(8))) unsigned short ush8;
typedef unsigned long long u64;

__device__ __forceinline__ unsigned short f2bf(float f) {
    __hip_bfloat16 h = __float2bfloat16(f);
    return *reinterpret_cast<unsigned short*>(&h);
}
__device__ __forceinline__ float bf2f(unsigned short u) {
    __hip_bfloat16 h = *reinterpret_cast<__hip_bfloat16*>(&u);
    return __bfloat162float(h);
}
__device__ __forceinline__ u64 umax64(u64 a, u64 b) { return a > b ? a : b; }
__device__ __forceinline__ u64 umin64(u64 a, u64 b) { return a < b ? a : b; }
__device__ __forceinline__ u64 clean6(u64 v, int lane) {
    #pragma unroll
    for (int j = 32; j; j >>= 1) {
        u64 o = __shfl_xor(v, j);
        v = ((lane & j) == 0) ? umax64(v, o) : umin64(v, o);
    }
    return v;
}

// ---------------- K0: fwT fragment-pack (0..255) | low (256..767) ----------------
union PrepShared {
    float tile[64][68];
    double gpm[513];
};
__global__ __launch_bounds__(256) void k_prep(
        const float* __restrict__ gp_w, const float* __restrict__ gp_b,
        const float* __restrict__ fw, const float* __restrict__ src,
        unsigned short* __restrict__ fwT_hi, unsigned short* __restrict__ fwT_lo,
        double* __restrict__ low) {
    __shared__ PrepShared u;
    int bid = blockIdx.x, t = threadIdx.x;
    if (bid < 256) {
        // ---- pack fw -> MFMA B-fragment order, bf16 hi/lo ----
        int k0 = bid * 64;
        int i = t >> 2;
        #pragma unroll
        for (int q = 0; q < 4; ++q) {
            int c = (t & 3) + q*4;
            float4 v = *reinterpret_cast<const float4*>(fw + (size_t)(k0 + i)*SIM + c*4);
            *reinterpret_cast<float4*>(&u.tile[i][c*4]) = v;
        }
        __syncthreads();
        #pragma unroll
        for (int c2 = 0; c2 < 2; ++c2) {
            int e = c2*256 + t;
            int kl = e >> 8, fn = (e >> 6) & 3, l = e & 63;
            int kk0 = kl*32 + ((l >> 4) * 8), n = fn*16 + (l & 15);
            ush8 hv, lv;
            #pragma unroll
            for (int j = 0; j < 8; ++j) {
                float f = u.tile[kk0 + j][n];
                unsigned short hb = f2bf(f);
                hv[j] = hb;
                lv[j] = f2bf(f - bf2f(hb));
            }
            size_t dst = ((size_t)((2*bid + kl)*4 + fn)*64 + l)*8;
            *reinterpret_cast<ush8*>(fwT_hi + dst) = hv;
            *reinterpret_cast<ush8*>(fwT_lo + dst) = lv;
        }
    } else {
        // ---- low role: self-contained gp means + 4 batch-0 row dots ----
        for (int h = t; h < HALFD; h += 256) {
            double s = 0.0;
            #pragma unroll
            for (int j = 0; j < 10; ++j) s += (double)gp_w[h*10 + j];
            u.gpm[h] = s / 10.0;
        }
        if (t == 0) {
            double sb = 0.0;
            #pragma unroll
            for (int j = 0; j < 10; ++j) sb += (double)gp_b[j];
            u.gpm[512] = sb / 10.0;
        }
        __syncthreads();
        int r = (bid - 256)*4 + (t >> 6);      // 0..2047
        int lane = t & 63;
        const float4* s4 = reinterpret_cast<const float4*>(src + (size_t)r * DMODEL);
        float4 x0 = s4[128 + lane];
        float4 x1 = s4[192 + lane];
        const double* g0 = u.gpm + lane*4;
        const double* g1 = u.gpm + 256 + lane*4;
        double d = (double)x0.x*g0[0] + (double)x0.y*g0[1] + (double)x0.z*g0[2] + (double)x0.w*g0[3]
                 + (double)x1.x*g1[0] + (double)x1.y*g1[1] + (double)x1.z*g1[2] + (double)x1.w*g1[3];
        #pragma unroll
        for (int o = 32; o; o >>= 1) d += __shfl_xor(d, o);
        if (lane == 0) low[r] = d + u.gpm[512];
    }
}

// ---------------- K2: topk — wave-register bitonic ----------------
__global__ __launch_bounds__(256) void k_topk(
        const double* __restrict__ low, const float* __restrict__ pool,
        u64* __restrict__ cand) {
    __shared__ double lowp[PLEN];
    __shared__ u64 wl[4][64];
    int t = threadIdx.x, lane = t & 63, w = t >> 6;
    int p = blockIdx.x >> 3, q = blockIdx.x & 7;
    if (t < PLEN) lowp[t] = low[p*PLEN + t];
    __syncthreads();
    u64 v[2];
    #pragma unroll
    for (int cc = 0; cc < 2; ++cc) {
        int n = q*512 + (w*2 + cc)*64 + lane;
        const float4* p4 = reinterpret_cast<const float4*>(pool + (size_t)n*PLEN);
        double s = 0.0;
        #pragma unroll
        for (int r2 = 0; r2 < 8; ++r2) {
            float4 vv = p4[r2];
            s += (double)vv.x*lowp[r2*4] + (double)vv.y*lowp[r2*4+1]
               + (double)vv.z*lowp[r2*4+2] + (double)vv.w*lowp[r2*4+3];
        }
        u64 ub = (u64)__double_as_longlong(s);
        u64 okey = ub ^ (((u64)((long long)ub >> 63)) | 0x8000000000000000ULL);
        v[cc] = (okey & ~0xFFFULL) | (u64)(0xFFF - n);
    }
    #pragma unroll
    for (int kk = 2; kk <= 64; kk <<= 1) {
        #pragma unroll
        for (int j = kk >> 1; j; j >>= 1) {
            #pragma unroll
            for (int cc = 0; cc < 2; ++cc) {
                u64 o = __shfl_xor(v[cc], j);
                bool keepMax = ((lane & kk) == 0) == ((lane & j) == 0);
                v[cc] = keepMax ? umax64(v[cc], o) : umin64(v[cc], o);
            }
        }
    }
    u64 rb = __shfl(v[1], 63 - lane);
    u64 m = umax64(v[0], rb);
    m = clean6(m, lane);
    wl[w][lane] = m;
    __syncthreads();
    if (w == 0) {
        u64 a = umax64(wl[0][lane], wl[1][63 - lane]); a = clean6(a, lane);
        u64 b = umax64(wl[2][lane], wl[3][63 - lane]); b = clean6(b, lane);
        u64 r2 = __shfl(b, 63 - lane);
        u64 f = umax64(a, r2); f = clean6(f, lane);
        cand[(size_t)(p*8 + q)*SIM + lane] = f;
    }
}

// ---------------- K3: logits MFMA — direct-global A (coalesced 256B/row), packed B, no LDS ----------------
__global__ __launch_bounds__(256) void k_logits(
        const float* __restrict__ src,
        const unsigned short* __restrict__ fwT_hi, const unsigned short* __restrict__ fwT_lo,
        float* __restrict__ part, int nks) {
    int t = threadIdx.x, lane = t & 63, w = t >> 6;
    int mt = blockIdx.x / nks, ks = blockIdx.x - mt*nks;
    int kchunk = KDIM / nks, nstep = kchunk >> 6;
    int r0 = mt*64;
    int ml = lane & 15, kg = lane >> 4;
    int Rrow = r0 + w*16 + ml;
    int bb = Rrow >> 6, prow = Rrow & 63;
    const float* xrow = src + ((size_t)(bb*SEQ + prow*PLEN))*DMODEL + HALFD;
    int kblk_base = (ks*kchunk) >> 5;
    f32x4 acc[4] = {};
    for (int step = 0; step < nstep; ++step) {
        int k0 = ks*kchunk + step*64;
        int l = k0 >> 9, h0 = k0 & 511;          // 64-chunk never crosses l
        const float* ap = xrow + (size_t)l*DMODEL + h0 + kg*8;
        float4 va0 = *reinterpret_cast<const float4*>(ap);
        float4 va1 = *reinterpret_cast<const float4*>(ap + 4);
        float4 vb0 = *reinterpret_cast<const float4*>(ap + 32);
        float4 vb1 = *reinterpret_cast<const float4*>(ap + 36);
        s8v ah0, al0, ah1, al1;
        float fa[8] = {va0.x,va0.y,va0.z,va0.w,va1.x,va1.y,va1.z,va1.w};
        float fbv[8] = {vb0.x,vb0.y,vb0.z,vb0.w,vb1.x,vb1.y,vb1.z,vb1.w};
        #pragma unroll
        for (int j = 0; j < 8; ++j) {
            unsigned short hb = f2bf(fa[j]);
            ah0[j] = (short)hb;
            al0[j] = (short)f2bf(fa[j] - bf2f(hb));
            unsigned short hb2 = f2bf(fbv[j]);
            ah1[j] = (short)hb2;
            al1[j] = (short)f2bf(fbv[j] - bf2f(hb2));
        }
        int kblk0 = kblk_base + step*2;
        #pragma unroll
        for (int fn = 0; fn < 4; ++fn) {
            size_t off0 = ((size_t)(kblk0*4 + fn)*64 + lane)*8;
            size_t off1 = ((size_t)((kblk0+1)*4 + fn)*64 + lane)*8;
            s8v bh0 = *reinterpret_cast<const s8v*>(fwT_hi + off0);
            s8v bl0 = *reinterpret_cast<const s8v*>(fwT_lo + off0);
            s8v bh1 = *reinterpret_cast<const s8v*>(fwT_hi + off1);
            s8v bl1 = *reinterpret_cast<const s8v*>(fwT_lo + off1);
            acc[fn] = __builtin_amdgcn_mfma_f32_16x16x32_bf16(ah0, bh0, acc[fn], 0, 0, 0);
            acc[fn] = __builtin_amdgcn_mfma_f32_16x16x32_bf16(ah0, bl0, acc[fn], 0, 0, 0);
            acc[fn] = __builtin_amdgcn_mfma_f32_16x16x32_bf16(al0, bh0, acc[fn], 0, 0, 0);
            acc[fn] = __builtin_amdgcn_mfma_f32_16x16x32_bf16(ah1, bh1, acc[fn], 0, 0, 0);
            acc[fn] = __builtin_amdgcn_mfma_f32_16x16x32_bf16(ah1, bl1, acc[fn], 0, 0, 0);
            acc[fn] = __builtin_amdgcn_mfma_f32_16x16x32_bf16(al1, bh1, acc[fn], 0, 0, 0);
        }
    }
    float* pout = part + (size_t)(mt*nks + ks)*4096;
    #pragma unroll
    for (int fn = 0; fn < 4; ++fn)
        #pragma unroll
        for (int r = 0; r < 4; ++r)
            pout[(w*16 + kg*4 + r)*64 + fn*16 + ml] = acc[fn][r];
}

// ---------------- K4: out — softmax + merge + copy + fuse/recover GEMM, full-row writes ----------------
__global__ __launch_bounds__(256) void k_out(
        const float* __restrict__ part, const float* __restrict__ fb,
        const u64* __restrict__ cand, const float* __restrict__ pool,
        const float* __restrict__ rw, const float* __restrict__ rb,
        const float* __restrict__ src, float* __restrict__ out,
        float* __restrict__ pad, int nks) {
    __shared__ float A_T[SIM][36];
    __shared__ float rws[64][132];
    __shared__ float routeS[64];
    __shared__ int   selS[64];
    int row = blockIdx.x;                    // b*64+p
    int b = row >> 6, p = row & 63;
    int t = threadIdx.x, lane = t & 63, w = t >> 6;
    if (w == 0) {
        // softmax for this row from K-split partials
        float v = fb[lane];
        for (int ks = 0; ks < nks; ++ks)
            v += part[(size_t)(b*nks + ks)*4096 + p*64 + lane];
        float m = v;
        #pragma unroll
        for (int o = 32; o; o >>= 1) m = fmaxf(m, __shfl_xor(m, o));
        float e = expf(v - m);
        float sum = e;
        #pragma unroll
        for (int o = 32; o; o >>= 1) sum += __shfl_xor(sum, o);
        routeS[lane] = e / sum;
    } else if (w == 1) {
        // top-64 merge of 8 sorted candidate lists for patch p
        const u64* c = cand + (size_t)p*8*SIM;
        u64 a = umax64(c[lane],         c[1*SIM + 63 - lane]); a = clean6(a, lane);
        u64 bq = umax64(c[2*SIM + lane], c[3*SIM + 63 - lane]); bq = clean6(bq, lane);
        u64 d = umax64(c[4*SIM + lane], c[5*SIM + 63 - lane]); d = clean6(d, lane);
        u64 e = umax64(c[6*SIM + lane], c[7*SIM + 63 - lane]); e = clean6(e, lane);
        u64 ab = umax64(a, __shfl(bq, 63 - lane)); ab = clean6(ab, lane);
        u64 de = umax64(d, __shfl(e, 63 - lane)); de = clean6(de, lane);
        u64 f  = umax64(ab, __shfl(de, 63 - lane)); f = clean6(f, lane);
        selS[lane] = 0xFFF - (int)(f & 0xFFFULL);
    } else {
        // copy role: first halves of this block's 32 rows
        int c = (w - 2)*64 + lane;           // 0..127 (float4 col)
        const float4* s4 = reinterpret_cast<const float4*>(src);
        float4* o4 = reinterpret_cast<float4*>(out);
        size_t base = ((size_t)(b*SEQ + p*PLEN))*256;
        #pragma unroll
        for (int rr = 0; rr < 32; ++rr)
            o4[base + rr*256 + c] = s4[base + rr*256 + c];
    }
    __syncthreads();
    #pragma unroll
    for (int q = 0; q < 8; ++q) {            // A_T[s][l] = route[s]*pool[sel[s]][l]
        int e = t + q*256;
        int s = e >> 5, l = e & 31;
        A_T[s][l] = routeS[s] * pool[(size_t)selS[s]*PLEN + l];
    }
    __syncthreads();
    if (t < 32) {                            // padding row-sum
        float ps = 0.f;
        #pragma unroll
        for (int s = 0; s < 64; ++s) ps += A_T[s][t];
        pad[(size_t)b*2*SEQ + SEQ + p*PLEN + t] = ps;
    } else if (t < 64) {                     // zeros in first half of padding_out
        pad[(size_t)b*2*SEQ + p*PLEN + (t - 32)] = 0.f;
    }
    int l0  = (t >> 5) * 4;
    int h04 = (t & 31) * 4;
    for (int hc = 0; hc < HALFD; hc += 128) {
        #pragma unroll
        for (int q = 0; q < 8; ++q) {        // stage recover_w[:, hc:hc+128]
            int fi = t + q*256;
            int r = fi >> 5, c4 = fi & 31;
            float4 v = *reinterpret_cast<const float4*>(rw + (size_t)r*HALFD + hc + c4*4);
            *reinterpret_cast<float4*>(&rws[r][c4*4]) = v;
        }
        __syncthreads();
        float acc[4][4] = {};
        #pragma unroll 8
        for (int s = 0; s < 64; ++s) {
            float4 av = *reinterpret_cast<float4*>(&A_T[s][l0]);
            float4 wv = *reinterpret_cast<float4*>(&rws[s][h04]);
            acc[0][0] += av.x*wv.x; acc[0][1] += av.x*wv.y; acc[0][2] += av.x*wv.z; acc[0][3] += av.x*wv.w;
            acc[1][0] += av.y*wv.x; acc[1][1] += av.y*wv.y; acc[1][2] += av.y*wv.z; acc[1][3] += av.y*wv.w;
            acc[2][0] += av.z*wv.x; acc[2][1] += av.z*wv.y; acc[2][2] += av.z*wv.z; acc[2][3] += av.z*wv.w;
            acc[3][0] += av.w*wv.x; acc[3][1] += av.w*wv.y; acc[3][2] += av.w*wv.z; acc[3][3] += av.w*wv.w;
        }
        int h = hc + h04;
        float4 bias = *reinterpret_cast<const float4*>(rb + h);
        #pragma unroll
        for (int i = 0; i < 4; ++i) {
            int l = l0 + i;
            float4 v = { acc[i][0] + bias.x, acc[i][1] + bias.y,
                         acc[i][2] + bias.z, acc[i][3] + bias.w };
            *reinterpret_cast<float4*>(out + ((size_t)(b*SEQ + p*PLEN + l))*DMODEL + HALFD + h) = v;
        }
        __syncthreads();
    }
}

static const void* by_size(void* const* d_in, const int* in_sizes, int n_in,
                           int want, int fallback) {
    for (int i = 0; i < n_in; ++i) if (in_sizes[i] == want) return d_in[i];
    return d_in[fallback];
}

extern "C" void kernel_launch(void* const* d_in, const int* in_sizes, int n_in,
                              void* d_out, int out_size, void* d_ws, size_t ws_size,
                              hipStream_t stream) {
    const float* src  = (const float*)by_size(d_in, in_sizes, n_in, NB*SEQ*DMODEL, 0);
    const float* pool = (const float*)by_size(d_in, in_sizes, n_in, PNUM*PLEN, 1);
    const float* fw   = (const float*)by_size(d_in, in_sizes, n_in, KDIM*SIM, 2);
    const float* fb   = (const float*)by_size(d_in, in_sizes, n_in, SIM, 3);
    const float* rw   = (const float*)by_size(d_in, in_sizes, n_in, SIM*HALFD, 4);
    const float* rb   = (const float*)by_size(d_in, in_sizes, n_in, HALFD, 5);
    const float* gpw  = (const float*)by_size(d_in, in_sizes, n_in, HALFD*10, 6);
    const float* gpb  = (const float*)by_size(d_in, in_sizes, n_in, 10, 7);
    float* out = (float*)d_out;
    float* pad = out + OUT0;

    int nks = (ws_size >= (size_t)(16u << 20)) ? 32 : 8;

    unsigned short* fwT_hi = (unsigned short*)d_ws;                     // 2 MB
    unsigned short* fwT_lo = fwT_hi + (size_t)SIM*KDIM;                 // 2 MB
    double* low  = (double*)(fwT_lo + (size_t)SIM*KDIM);                // 16 KB
    u64*   cand  = (u64*)(low + 2048);                                  // 256 KB
    float* part  = (float*)(cand + (size_t)NPATCH*8*SIM);               // nks * 256 KB

    hipLaunchKernelGGL(k_prep,   dim3(768),    dim3(256), 0, stream, gpw, gpb, fw, src, fwT_hi, fwT_lo, low);
    hipLaunchKernelGGL(k_topk,   dim3(512),    dim3(256), 0, stream, low, pool, cand);
    hipLaunchKernelGGL(k_logits, dim3(16*nks), dim3(256), 0, stream, src, fwT_hi, fwT_lo, part, nks);
    hipLaunchKernelGGL(k_out,    dim3(MROWS),  dim3(256), 0, stream, part, fb, cand, pool, rw, rb, src, out, pad, nks);
}

// Round 14
// 111.204 us; speedup vs baseline: 1.3479x; 1.0155x over previous
//
#include <hip/hip_runtime.h>
#include <hip/hip_bf16.h>

#define NB 16
#define DMODEL 1024
#define HALFD 512
#define PNUM 4096
#define PLEN 32
#define SEQ 2048
#define SIM 64
#define NPATCH 64
#define NROWS (NB*SEQ)        // 32768 sequence rows
#define MROWS (NB*NPATCH)     // 1024 (b,p) rows
#define KDIM (PLEN*HALFD)     // 16384
#define OUT0 ((size_t)NB*SEQ*DMODEL)

typedef __attribute__((ext_vector_type(8))) short s8v;          // 8 bf16 (4 VGPR)
typedef __attribute__((ext_vector_type(4))) float f32x4;
typedef __attribute__((ext_vector_type(8))) unsigned short ush8;
typedef unsigned long long u64;

__device__ __forceinline__ unsigned short f2bf(float f) {
    __hip_bfloat16 h = __float2bfloat16(f);
    return *reinterpret_cast<unsigned short*>(&h);
}
__device__ __forceinline__ float bf2f(unsigned short u) {
    __hip_bfloat16 h = *reinterpret_cast<__hip_bfloat16*>(&u);
    return __bfloat162float(h);
}
__device__ __forceinline__ u64 umax64(u64 a, u64 b) { return a > b ? a : b; }
__device__ __forceinline__ u64 umin64(u64 a, u64 b) { return a < b ? a : b; }
__device__ __forceinline__ u64 clean6(u64 v, int lane) {
    #pragma unroll
    for (int j = 32; j; j >>= 1) {
        u64 o = __shfl_xor(v, j);
        v = ((lane & j) == 0) ? umax64(v, o) : umin64(v, o);
    }
    return v;
}

// ---- K0: fw pack (0..255) | low (256..767) | rw pack (768..783) ----
union PrepShared {
    float tile[64][68];
    double gpm[513];
};
__global__ __launch_bounds__(256) void k_prep(
        const float* __restrict__ gp_w, const float* __restrict__ gp_b,
        const float* __restrict__ fw, const float* __restrict__ rw,
        const float* __restrict__ src,
        unsigned short* __restrict__ fwT_hi, unsigned short* __restrict__ fwT_lo,
        unsigned short* __restrict__ rwf_hi, unsigned short* __restrict__ rwf_lo,
        double* __restrict__ low) {
    __shared__ PrepShared u;
    int bid = blockIdx.x, t = threadIdx.x;
    if (bid < 256) {
        // ---- pack fw -> MFMA B-fragment order, bf16 hi/lo ----
        int k0 = bid * 64;
        int i = t >> 2;
        #pragma unroll
        for (int q = 0; q < 4; ++q) {
            int c = (t & 3) + q*4;
            float4 v = *reinterpret_cast<const float4*>(fw + (size_t)(k0 + i)*SIM + c*4);
            *reinterpret_cast<float4*>(&u.tile[i][c*4]) = v;
        }
        __syncthreads();
        #pragma unroll
        for (int c2 = 0; c2 < 2; ++c2) {
            int e = c2*256 + t;
            int kl = e >> 8, fn = (e >> 6) & 3, l = e & 63;
            int kk0 = kl*32 + ((l >> 4) * 8), n = fn*16 + (l & 15);
            ush8 hv, lv;
            #pragma unroll
            for (int j = 0; j < 8; ++j) {
                float f = u.tile[kk0 + j][n];
                unsigned short hb = f2bf(f);
                hv[j] = hb;
                lv[j] = f2bf(f - bf2f(hb));
            }
            size_t dst = ((size_t)((2*bid + kl)*4 + fn)*64 + l)*8;
            *reinterpret_cast<ush8*>(fwT_hi + dst) = hv;
            *reinterpret_cast<ush8*>(fwT_lo + dst) = lv;
        }
    } else if (bid < 768) {
        // ---- low role: self-contained gp means + 4 batch-0 row dots ----
        for (int h = t; h < HALFD; h += 256) {
            double s = 0.0;
            #pragma unroll
            for (int j = 0; j < 10; ++j) s += (double)gp_w[h*10 + j];
            u.gpm[h] = s / 10.0;
        }
        if (t == 0) {
            double sb = 0.0;
            #pragma unroll
            for (int j = 0; j < 10; ++j) sb += (double)gp_b[j];
            u.gpm[512] = sb / 10.0;
        }
        __syncthreads();
        int r = (bid - 256)*4 + (t >> 6);      // 0..2047
        int lane = t & 63;
        const float4* s4 = reinterpret_cast<const float4*>(src + (size_t)r * DMODEL);
        float4 x0 = s4[128 + lane];
        float4 x1 = s4[192 + lane];
        const double* g0 = u.gpm + lane*4;
        const double* g1 = u.gpm + 256 + lane*4;
        double d = (double)x0.x*g0[0] + (double)x0.y*g0[1] + (double)x0.z*g0[2] + (double)x0.w*g0[3]
                 + (double)x1.x*g1[0] + (double)x1.y*g1[1] + (double)x1.z*g1[2] + (double)x1.w*g1[3];
        #pragma unroll
        for (int o = 32; o; o >>= 1) d += __shfl_xor(d, o);
        if (lane == 0) low[r] = d + u.gpm[512];
    } else {
        // ---- pack rw (64x512) -> MFMA B-fragment order, bf16 hi/lo ----
        int lane = t & 63, q = t >> 6;
        int idx = (bid - 768)*4 + q;           // 0..63 = (ks,fn)
        int ks = idx >> 5, fn = idx & 31;
        int ml = lane & 15, kg = lane >> 4;
        ush8 hv, lv;
        #pragma unroll
        for (int j = 0; j < 8; ++j) {
            float f = rw[(size_t)(ks*32 + kg*8 + j)*HALFD + fn*16 + ml];
            unsigned short hb = f2bf(f);
            hv[j] = hb;
            lv[j] = f2bf(f - bf2f(hb));
        }
        size_t dst = ((size_t)idx*64 + lane)*8;
        *reinterpret_cast<ush8*>(rwf_hi + dst) = hv;
        *reinterpret_cast<ush8*>(rwf_lo + dst) = lv;
    }
}

// ---------------- K2: topk — wave-register bitonic ----------------
__global__ __launch_bounds__(256) void k_topk(
        const double* __restrict__ low, const float* __restrict__ pool,
        u64* __restrict__ cand) {
    __shared__ double lowp[PLEN];
    __shared__ u64 wl[4][64];
    int t = threadIdx.x, lane = t & 63, w = t >> 6;
    int p = blockIdx.x >> 3, q = blockIdx.x & 7;
    if (t < PLEN) lowp[t] = low[p*PLEN + t];
    __syncthreads();
    u64 v[2];
    #pragma unroll
    for (int cc = 0; cc < 2; ++cc) {
        int n = q*512 + (w*2 + cc)*64 + lane;
        const float4* p4 = reinterpret_cast<const float4*>(pool + (size_t)n*PLEN);
        double s = 0.0;
        #pragma unroll
        for (int r2 = 0; r2 < 8; ++r2) {
            float4 vv = p4[r2];
            s += (double)vv.x*lowp[r2*4] + (double)vv.y*lowp[r2*4+1]
               + (double)vv.z*lowp[r2*4+2] + (double)vv.w*lowp[r2*4+3];
        }
        u64 ub = (u64)__double_as_longlong(s);
        u64 okey = ub ^ (((u64)((long long)ub >> 63)) | 0x8000000000000000ULL);
        v[cc] = (okey & ~0xFFFULL) | (u64)(0xFFF - n);
    }
    #pragma unroll
    for (int kk = 2; kk <= 64; kk <<= 1) {
        #pragma unroll
        for (int j = kk >> 1; j; j >>= 1) {
            #pragma unroll
            for (int cc = 0; cc < 2; ++cc) {
                u64 o = __shfl_xor(v[cc], j);
                bool keepMax = ((lane & kk) == 0) == ((lane & j) == 0);
                v[cc] = keepMax ? umax64(v[cc], o) : umin64(v[cc], o);
            }
        }
    }
    u64 rb2 = __shfl(v[1], 63 - lane);
    u64 m = umax64(v[0], rb2);
    m = clean6(m, lane);
    wl[w][lane] = m;
    __syncthreads();
    if (w == 0) {
        u64 a = umax64(wl[0][lane], wl[1][63 - lane]); a = clean6(a, lane);
        u64 b = umax64(wl[2][lane], wl[3][63 - lane]); b = clean6(b, lane);
        u64 r2 = __shfl(b, 63 - lane);
        u64 f = umax64(a, r2); f = clean6(f, lane);
        cand[(size_t)(p*8 + q)*SIM + lane] = f;
    }
}

// ---------------- K3: logits MFMA — direct-global A, packed B, no LDS ----------------
__global__ __launch_bounds__(256) void k_logits(
        const float* __restrict__ src,
        const unsigned short* __restrict__ fwT_hi, const unsigned short* __restrict__ fwT_lo,
        float* __restrict__ part, int nks) {
    int t = threadIdx.x, lane = t & 63, w = t >> 6;
    int mt = blockIdx.x / nks, ks = blockIdx.x - mt*nks;
    int kchunk = KDIM / nks, nstep = kchunk >> 6;
    int r0 = mt*64;
    int ml = lane & 15, kg = lane >> 4;
    int Rrow = r0 + w*16 + ml;
    int bb = Rrow >> 6, prow = Rrow & 63;
    const float* xrow = src + ((size_t)(bb*SEQ + prow*PLEN))*DMODEL + HALFD;
    int kblk_base = (ks*kchunk) >> 5;
    f32x4 acc[4] = {};
    for (int step = 0; step < nstep; ++step) {
        int k0 = ks*kchunk + step*64;
        int l = k0 >> 9, h0 = k0 & 511;
        const float* ap = xrow + (size_t)l*DMODEL + h0 + kg*8;
        float4 va0 = *reinterpret_cast<const float4*>(ap);
        float4 va1 = *reinterpret_cast<const float4*>(ap + 4);
        float4 vb0 = *reinterpret_cast<const float4*>(ap + 32);
        float4 vb1 = *reinterpret_cast<const float4*>(ap + 36);
        s8v ah0, al0, ah1, al1;
        float fa[8] = {va0.x,va0.y,va0.z,va0.w,va1.x,va1.y,va1.z,va1.w};
        float fbv[8] = {vb0.x,vb0.y,vb0.z,vb0.w,vb1.x,vb1.y,vb1.z,vb1.w};
        #pragma unroll
        for (int j = 0; j < 8; ++j) {
            unsigned short hb = f2bf(fa[j]);
            ah0[j] = (short)hb;
            al0[j] = (short)f2bf(fa[j] - bf2f(hb));
            unsigned short hb2 = f2bf(fbv[j]);
            ah1[j] = (short)hb2;
            al1[j] = (short)f2bf(fbv[j] - bf2f(hb2));
        }
        int kblk0 = kblk_base + step*2;
        #pragma unroll
        for (int fn = 0; fn < 4; ++fn) {
            size_t off0 = ((size_t)(kblk0*4 + fn)*64 + lane)*8;
            size_t off1 = ((size_t)((kblk0+1)*4 + fn)*64 + lane)*8;
            s8v bh0 = *reinterpret_cast<const s8v*>(fwT_hi + off0);
            s8v bl0 = *reinterpret_cast<const s8v*>(fwT_lo + off0);
            s8v bh1 = *reinterpret_cast<const s8v*>(fwT_hi + off1);
            s8v bl1 = *reinterpret_cast<const s8v*>(fwT_lo + off1);
            acc[fn] = __builtin_amdgcn_mfma_f32_16x16x32_bf16(ah0, bh0, acc[fn], 0, 0, 0);
            acc[fn] = __builtin_amdgcn_mfma_f32_16x16x32_bf16(ah0, bl0, acc[fn], 0, 0, 0);
            acc[fn] = __builtin_amdgcn_mfma_f32_16x16x32_bf16(al0, bh0, acc[fn], 0, 0, 0);
            acc[fn] = __builtin_amdgcn_mfma_f32_16x16x32_bf16(ah1, bh1, acc[fn], 0, 0, 0);
            acc[fn] = __builtin_amdgcn_mfma_f32_16x16x32_bf16(ah1, bl1, acc[fn], 0, 0, 0);
            acc[fn] = __builtin_amdgcn_mfma_f32_16x16x32_bf16(al1, bh1, acc[fn], 0, 0, 0);
        }
    }
    float* pout = part + (size_t)(mt*nks + ks)*4096;
    #pragma unroll
    for (int fn = 0; fn < 4; ++fn)
        #pragma unroll
        for (int r = 0; r < 4; ++r)
            pout[(w*16 + kg*4 + r)*64 + fn*16 + ml] = acc[fn][r];
}

// ---- K4: out — softmax + merge + A build + MFMA recover GEMM + padding + copy ----
__global__ __launch_bounds__(256) void k_out(
        const float* __restrict__ part, const float* __restrict__ fb,
        const u64* __restrict__ cand, const float* __restrict__ pool,
        const unsigned short* __restrict__ rwf_hi, const unsigned short* __restrict__ rwf_lo,
        const float* __restrict__ rb, const float* __restrict__ src,
        float* __restrict__ out, float* __restrict__ pad, int nks) {
    __shared__ float A_T[SIM][36];           // [k=s][m=l]
    __shared__ float routeS[64];
    __shared__ int   selS[64];
    int row = blockIdx.x;                    // b*64+p
    int b = row >> 6, p = row & 63;
    int t = threadIdx.x, lane = t & 63, w = t >> 6;
    if (w == 0) {
        float v = fb[lane];
        for (int ks = 0; ks < nks; ++ks)
            v += part[(size_t)(b*nks + ks)*4096 + p*64 + lane];
        float m = v;
        #pragma unroll
        for (int o = 32; o; o >>= 1) m = fmaxf(m, __shfl_xor(m, o));
        float e = expf(v - m);
        float sum = e;
        #pragma unroll
        for (int o = 32; o; o >>= 1) sum += __shfl_xor(sum, o);
        routeS[lane] = e / sum;
    } else if (w == 1) {
        const u64* c = cand + (size_t)p*8*SIM;
        u64 a = umax64(c[lane],         c[1*SIM + 63 - lane]); a = clean6(a, lane);
        u64 bq = umax64(c[2*SIM + lane], c[3*SIM + 63 - lane]); bq = clean6(bq, lane);
        u64 d = umax64(c[4*SIM + lane], c[5*SIM + 63 - lane]); d = clean6(d, lane);
        u64 e = umax64(c[6*SIM + lane], c[7*SIM + 63 - lane]); e = clean6(e, lane);
        u64 ab = umax64(a, __shfl(bq, 63 - lane)); ab = clean6(ab, lane);
        u64 de = umax64(d, __shfl(e, 63 - lane)); de = clean6(de, lane);
        u64 f  = umax64(ab, __shfl(de, 63 - lane)); f = clean6(f, lane);
        selS[lane] = 0xFFF - (int)(f & 0xFFFULL);
    }
    __syncthreads();
    #pragma unroll
    for (int q = 0; q < 8; ++q) {            // A_T[s][l] = route[s]*pool[sel[s]][l]
        int e = t + q*256;
        int s = e >> 5, l = e & 31;
        A_T[s][l] = routeS[s] * pool[(size_t)selS[s]*PLEN + l];
    }
    __syncthreads();
    if (t < 32) {                            // padding row-sum
        float ps = 0.f;
        #pragma unroll
        for (int s = 0; s < 64; ++s) ps += A_T[s][t];
        pad[(size_t)b*2*SEQ + SEQ + p*PLEN + t] = ps;
    } else if (t < 64) {
        pad[(size_t)b*2*SEQ + p*PLEN + (t - 32)] = 0.f;
    }
    // A fragments: a[j] = A[m = mt*16+ml][k = ks*32 + kg*8 + j], split bf16
    int ml = lane & 15, kg = lane >> 4;
    s8v ah[2][2], al[2][2];                  // [mt][ks]
    #pragma unroll
    for (int mt = 0; mt < 2; ++mt)
        #pragma unroll
        for (int ks = 0; ks < 2; ++ks) {
            #pragma unroll
            for (int j = 0; j < 8; ++j) {
                float f = A_T[ks*32 + kg*8 + j][mt*16 + ml];
                unsigned short hb = f2bf(f);
                ah[mt][ks][j] = (short)hb;
                al[mt][ks][j] = (short)f2bf(f - bf2f(hb));
            }
        }
    // MFMA: wave w covers N cols [w*128, w*128+128)
    size_t orow0 = ((size_t)(b*SEQ + p*PLEN))*DMODEL + HALFD;
    #pragma unroll
    for (int nt = 0; nt < 8; ++nt) {
        int fng = w*8 + nt;
        f32x4 acc0 = {}, acc1 = {};
        #pragma unroll
        for (int ks = 0; ks < 2; ++ks) {
            size_t off = ((size_t)(ks*32 + fng)*64 + lane)*8;
            s8v bh = *reinterpret_cast<const s8v*>(rwf_hi + off);
            s8v bl = *reinterpret_cast<const s8v*>(rwf_lo + off);
            acc0 = __builtin_amdgcn_mfma_f32_16x16x32_bf16(ah[0][ks], bh, acc0, 0, 0, 0);
            acc0 = __builtin_amdgcn_mfma_f32_16x16x32_bf16(ah[0][ks], bl, acc0, 0, 0, 0);
            acc0 = __builtin_amdgcn_mfma_f32_16x16x32_bf16(al[0][ks], bh, acc0, 0, 0, 0);
            acc1 = __builtin_amdgcn_mfma_f32_16x16x32_bf16(ah[1][ks], bh, acc1, 0, 0, 0);
            acc1 = __builtin_amdgcn_mfma_f32_16x16x32_bf16(ah[1][ks], bl, acc1, 0, 0, 0);
            acc1 = __builtin_amdgcn_mfma_f32_16x16x32_bf16(al[1][ks], bh, acc1, 0, 0, 0);
        }
        int n = fng*16 + ml;
        float bias = rb[n];
        #pragma unroll
        for (int r = 0; r < 4; ++r) {
            int m0 = kg*4 + r;
            out[orow0 + (size_t)m0*DMODEL + n]        = acc0[r] + bias;
            out[orow0 + (size_t)(16 + m0)*DMODEL + n] = acc1[r] + bias;
        }
    }
    // copy first halves of this block's 32 rows
    const float4* s4 = reinterpret_cast<const float4*>(src);
    float4* o4 = reinterpret_cast<float4*>(out);
    size_t base = ((size_t)(b*SEQ + p*PLEN))*256;
    #pragma unroll
    for (int e = 0; e < 16; ++e) {
        int idx = e*256 + t;                 // 0..4095
        int rr = idx >> 7, c = idx & 127;
        o4[base + rr*256 + c] = s4[base + rr*256 + c];
    }
}

static const void* by_size(void* const* d_in, const int* in_sizes, int n_in,
                           int want, int fallback) {
    for (int i = 0; i < n_in; ++i) if (in_sizes[i] == want) return d_in[i];
    return d_in[fallback];
}

extern "C" void kernel_launch(void* const* d_in, const int* in_sizes, int n_in,
                              void* d_out, int out_size, void* d_ws, size_t ws_size,
                              hipStream_t stream) {
    const float* src  = (const float*)by_size(d_in, in_sizes, n_in, NB*SEQ*DMODEL, 0);
    const float* pool = (const float*)by_size(d_in, in_sizes, n_in, PNUM*PLEN, 1);
    const float* fw   = (const float*)by_size(d_in, in_sizes, n_in, KDIM*SIM, 2);
    const float* fb   = (const float*)by_size(d_in, in_sizes, n_in, SIM, 3);
    const float* rw   = (const float*)by_size(d_in, in_sizes, n_in, SIM*HALFD, 4);
    const float* rb   = (const float*)by_size(d_in, in_sizes, n_in, HALFD, 5);
    const float* gpw  = (const float*)by_size(d_in, in_sizes, n_in, HALFD*10, 6);
    const float* gpb  = (const float*)by_size(d_in, in_sizes, n_in, 10, 7);
    float* out = (float*)d_out;
    float* pad = out + OUT0;

    int nks = (ws_size >= (size_t)(16u << 20)) ? 32 : 8;

    unsigned short* fwT_hi = (unsigned short*)d_ws;                     // 2 MB
    unsigned short* fwT_lo = fwT_hi + (size_t)SIM*KDIM;                 // 2 MB
    unsigned short* rwf_hi = fwT_lo + (size_t)SIM*KDIM;                 // 64 KB
    unsigned short* rwf_lo = rwf_hi + (size_t)SIM*HALFD;                // 64 KB
    double* low  = (double*)(rwf_lo + (size_t)SIM*HALFD);               // 16 KB
    u64*   cand  = (u64*)(low + 2048);                                  // 256 KB
    float* part  = (float*)(cand + (size_t)NPATCH*8*SIM);               // nks * 256 KB

    hipLaunchKernelGGL(k_prep,   dim3(784),    dim3(256), 0, stream,
                       gpw, gpb, fw, rw, src, fwT_hi, fwT_lo, rwf_hi, rwf_lo, low);
    hipLaunchKernelGGL(k_topk,   dim3(512),    dim3(256), 0, stream, low, pool, cand);
    hipLaunchKernelGGL(k_logits, dim3(16*nks), dim3(256), 0, stream, src, fwT_hi, fwT_lo, part, nks);
    hipLaunchKernelGGL(k_out,    dim3(MROWS),  dim3(256), 0, stream,
                       part, fb, cand, pool, rwf_hi, rwf_lo, rb, src, out, pad, nks);
}